// Round 2
// baseline (42.157 us; speedup 1.0000x reference)
//
#include <hip/hip_runtime.h>

#define B_ 2
#define N_ 28
#define D_ 128
#define H_ 8
#define DK_ 16
#define R_ (B_ * N_ * N_)   // 1568 rows of the flattened (b,n1,n2) axis
#define ROWS_PER_BLK 8      // 1568 / 8 = 196 blocks exactly
#define YG_ 4               // y's per attn block (28 = 7 * 4)

// ---------------------------------------------------------------------------
// Kernel 1: all four projections  Y_p = X_p @ W_p^T
//   p = 0: lk = key  @ Wlk^T ; p = 1: rk = key @ Wrk^T
//   p = 2: lv = value@ Wlv^T ; p = 3: rv = value@ Wrv^T
// Output layout in ws: [p][R_][128] floats.
// ---------------------------------------------------------------------------
__global__ __launch_bounds__(128) void proj4_kernel(
    const float* __restrict__ key, const float* __restrict__ value,
    const float* __restrict__ Wlk, const float* __restrict__ Wrk,
    const float* __restrict__ Wlv, const float* __restrict__ Wrv,
    float* __restrict__ ws) {
  const int p = blockIdx.y;
  const float* X = (p < 2) ? key : value;
  const float* W = (p == 0) ? Wlk : (p == 1) ? Wrk : (p == 2) ? Wlv : Wrv;
  float* Y = ws + (size_t)p * R_ * D_;

  const int r0 = blockIdx.x * ROWS_PER_BLK;
  const int c = threadIdx.x;  // output column 0..127

  __shared__ float xs[ROWS_PER_BLK][D_];
#pragma unroll
  for (int i = 0; i < ROWS_PER_BLK; ++i)
    xs[i][c] = X[(size_t)(r0 + i) * D_ + c];
  __syncthreads();

  const float4* w4 = reinterpret_cast<const float4*>(W + (size_t)c * D_);
  float acc[ROWS_PER_BLK];
#pragma unroll
  for (int i = 0; i < ROWS_PER_BLK; ++i) acc[i] = 0.f;

#pragma unroll
  for (int k = 0; k < D_ / 4; ++k) {
    const float4 wv = w4[k];
#pragma unroll
    for (int i = 0; i < ROWS_PER_BLK; ++i) {
      const float4 xv = reinterpret_cast<const float4*>(xs[i])[k];
      acc[i] += xv.x * wv.x + xv.y * wv.y + xv.z * wv.z + xv.w * wv.w;
    }
  }

#pragma unroll
  for (int i = 0; i < ROWS_PER_BLK; ++i)
    Y[(size_t)(r0 + i) * D_ + c] = acc[i];
}

// ---------------------------------------------------------------------------
// Kernel 2 (fused): per (b,x, y-group-of-4) block.
//   - stage lk(b,x,:) and lv(b,x,:) rows in LDS once (shared across the 4 y's)
//   - per y: scores over a (16-lane shfl dot), mask, softmax, PV product,
//            then out-row = x_row @ Wout^T directly to d_out.
// 128 threads = (h = tid>>4, d = tid&15) for attn; = out column for the GEMV.
// ---------------------------------------------------------------------------
__global__ __launch_bounds__(128) void attn_out_kernel(
    const float* __restrict__ ws, const int* __restrict__ mask,
    const float* __restrict__ Wout, float* __restrict__ out) {
  const float* lk = ws;
  const float* rk = ws + (size_t)1 * R_ * D_;
  const float* lv = ws + (size_t)2 * R_ * D_;
  const float* rv = ws + (size_t)3 * R_ * D_;

  const int yg = blockIdx.x % (N_ / YG_);  // y-group 0..6
  const int bx = blockIdx.x / (N_ / YG_);  // b*28 + x, 0..55
  const int b = bx / N_;
  const int tid = threadIdx.x;

  const int rowL = bx * N_;  // + a   (rows of lk / lv)

  __shared__ float s_lk[N_][D_];
  __shared__ float s_lv[N_][D_];
  __shared__ float s_x[D_];

#pragma unroll
  for (int a = 0; a < N_; ++a) {
    s_lk[a][tid] = lk[(size_t)(rowL + a) * D_ + tid];
    s_lv[a][tid] = lv[(size_t)(rowL + a) * D_ + tid];
  }
  __syncthreads();

  const float4* wrow = reinterpret_cast<const float4*>(Wout + (size_t)tid * D_);

  for (int j = 0; j < YG_; ++j) {
    const int y = yg * YG_ + j;
    const int rowR = b * N_ * N_ + y;  // + a*N_   (rows of rk / rv)

    float s[N_];
#pragma unroll
    for (int a = 0; a < N_; ++a) {
      float pr = s_lk[a][tid] * rk[(size_t)(rowR + a * N_) * D_ + tid];
      pr += __shfl_xor(pr, 1);
      pr += __shfl_xor(pr, 2);
      pr += __shfl_xor(pr, 4);
      pr += __shfl_xor(pr, 8);
      s[a] = pr * 0.25f;  // / sqrt(DK) = / 4
    }

    const int* mrow = mask + (size_t)rowL * N_ + y;  // mask[(rowL+a)*28 + y]
#pragma unroll
    for (int a = 0; a < N_; ++a)
      if (mrow[(size_t)a * N_] != 0) s[a] = -1e9f;

    float mx = -3.0e38f;
#pragma unroll
    for (int a = 0; a < N_; ++a) mx = fmaxf(mx, s[a]);
    float den = 0.f;
#pragma unroll
    for (int a = 0; a < N_; ++a) {
      s[a] = __expf(s[a] - mx);
      den += s[a];
    }
    const float inv = 1.0f / den;

    float xv = 0.f;
#pragma unroll
    for (int a = 0; a < N_; ++a) {
      xv += s[a] * s_lv[a][tid] * rv[(size_t)(rowR + a * N_) * D_ + tid];
    }
    s_x[tid] = xv * inv;
    __syncthreads();

    // out[bxy][tid] = sum_k s_x[k] * Wout[tid][k]
    float acc = 0.f;
    const float4* x4 = reinterpret_cast<const float4*>(s_x);
#pragma unroll
    for (int k = 0; k < D_ / 4; ++k) {
      const float4 xk = x4[k];
      const float4 wv = wrow[k];
      acc += xk.x * wv.x + xk.y * wv.y + xk.z * wv.z + xk.w * wv.w;
    }
    out[(size_t)(rowL + y) * D_ + tid] = acc;
    __syncthreads();  // protect s_x before next y overwrites it
  }
}

extern "C" void kernel_launch(void* const* d_in, const int* in_sizes, int n_in,
                              void* d_out, int out_size, void* d_ws,
                              size_t ws_size, hipStream_t stream) {
  // setup_inputs order:
  // 0 query (unused), 1 key, 2 value, 3 mask, 4 Wlk, 5 Wrk, 6 Wlv, 7 Wrv,
  // 8 Wq (unused), 9 Wout
  const float* key = (const float*)d_in[1];
  const float* value = (const float*)d_in[2];
  const int* mask = (const int*)d_in[3];
  const float* Wlk = (const float*)d_in[4];
  const float* Wrk = (const float*)d_in[5];
  const float* Wlv = (const float*)d_in[6];
  const float* Wrv = (const float*)d_in[7];
  const float* Wout = (const float*)d_in[9];
  float* out = (float*)d_out;

  float* ws = (float*)d_ws;

  proj4_kernel<<<dim3(R_ / ROWS_PER_BLK, 4), 128, 0, stream>>>(
      key, value, Wlk, Wrk, Wlv, Wrv, ws);
  attn_out_kernel<<<dim3((N_ / YG_) * B_ * N_), 128, 0, stream>>>(ws, mask,
                                                                  Wout, out);
}

// Round 4
// 36.692 us; speedup vs baseline: 1.1490x; 1.1490x over previous
//
#include <hip/hip_runtime.h>

#define B_ 2
#define N_ 28
#define D_ 128
#define H_ 8
#define DK_ 16
#define R_ (B_ * N_ * N_)   // 1568
#define ROWS_PER_BLK 8      // 1568 / 8 = 196 blocks per projection

// ---------------------------------------------------------------------------
// Kernel 1: all four projections  Y_p = X_p @ W_p^T
// Output layout in ws: [p][R_][128] floats.
// ---------------------------------------------------------------------------
__global__ __launch_bounds__(128) void proj4_kernel(
    const float* __restrict__ key, const float* __restrict__ value,
    const float* __restrict__ Wlk, const float* __restrict__ Wrk,
    const float* __restrict__ Wlv, const float* __restrict__ Wrv,
    float* __restrict__ ws) {
  const int p = blockIdx.y;
  const float* X = (p < 2) ? key : value;
  const float* W = (p == 0) ? Wlk : (p == 1) ? Wrk : (p == 2) ? Wlv : Wrv;
  float* Y = ws + (size_t)p * R_ * D_;

  const int r0 = blockIdx.x * ROWS_PER_BLK;
  const int c = threadIdx.x;  // output column 0..127

  __shared__ __align__(16) float xs[ROWS_PER_BLK][D_];
#pragma unroll
  for (int i = 0; i < ROWS_PER_BLK; ++i)
    xs[i][c] = X[(size_t)(r0 + i) * D_ + c];
  __syncthreads();

  const float4* w4 = reinterpret_cast<const float4*>(W + (size_t)c * D_);
  float acc[ROWS_PER_BLK];
#pragma unroll
  for (int i = 0; i < ROWS_PER_BLK; ++i) acc[i] = 0.f;

#pragma unroll
  for (int k = 0; k < D_ / 4; ++k) {
    const float4 wv = w4[k];
#pragma unroll
    for (int i = 0; i < ROWS_PER_BLK; ++i) {
      const float4 xv = reinterpret_cast<const float4*>(xs[i])[k];
      acc[i] += xv.x * wv.x + xv.y * wv.y + xv.z * wv.z + xv.w * wv.w;
    }
  }

#pragma unroll
  for (int i = 0; i < ROWS_PER_BLK; ++i)
    Y[(size_t)(r0 + i) * D_ + c] = acc[i];
}

// ---------------------------------------------------------------------------
// Kernel 2: per (b,x,y) block (1568 blocks): attention over a, then
// out-row = x_row @ Wout^T directly to d_out (one LDS round-trip).
// 128 threads = (h = tid>>4, d = tid&15) for attn; = out column for the GEMV.
// ---------------------------------------------------------------------------
__global__ __launch_bounds__(128) void attn_out_kernel(
    const float* __restrict__ ws, const int* __restrict__ mask,
    const float* __restrict__ Wout, float* __restrict__ out) {
  const float* lk = ws;
  const float* rk = ws + (size_t)1 * R_ * D_;
  const float* lv = ws + (size_t)2 * R_ * D_;
  const float* rv = ws + (size_t)3 * R_ * D_;

  const int bxy = blockIdx.x;   // (b*28 + x)*28 + y
  const int y = bxy % N_;
  const int bx = bxy / N_;      // b*28 + x
  const int b = bx / N_;
  const int tid = threadIdx.x;

  const int rowL = bx * N_;          // + a      (rows of lk / lv)
  const int rowR = b * N_ * N_ + y;  // + a*N_   (rows of rk / rv)

  float s[N_];
#pragma unroll
  for (int a = 0; a < N_; ++a) {
    float pr = lk[(size_t)(rowL + a) * D_ + tid] *
               rk[(size_t)(rowR + a * N_) * D_ + tid];
    pr += __shfl_xor(pr, 1);
    pr += __shfl_xor(pr, 2);
    pr += __shfl_xor(pr, 4);
    pr += __shfl_xor(pr, 8);
    s[a] = pr * 0.25f;  // / sqrt(DK) = / 4
  }

  const int* mrow = mask + (size_t)rowL * N_ + y;  // mask[(rowL+a)*28 + y]
#pragma unroll
  for (int a = 0; a < N_; ++a)
    if (mrow[(size_t)a * N_] != 0) s[a] = -1e9f;

  float mx = -3.0e38f;
#pragma unroll
  for (int a = 0; a < N_; ++a) mx = fmaxf(mx, s[a]);
  float den = 0.f;
#pragma unroll
  for (int a = 0; a < N_; ++a) {
    s[a] = __expf(s[a] - mx);
    den += s[a];
  }
  const float inv = 1.0f / den;

  float xv = 0.f;
#pragma unroll
  for (int a = 0; a < N_; ++a) {
    xv += s[a] * lv[(size_t)(rowL + a) * D_ + tid] *
          rv[(size_t)(rowR + a * N_) * D_ + tid];
  }

  __shared__ __align__(16) float s_x[D_];
  s_x[tid] = xv * inv;
  __syncthreads();

  // out[bxy][tid] = sum_k s_x[k] * Wout[tid][k]
  const float4* wrow = reinterpret_cast<const float4*>(Wout + (size_t)tid * D_);
  const float4* x4 = reinterpret_cast<const float4*>(s_x);
  float acc = 0.f;
#pragma unroll
  for (int k = 0; k < D_ / 4; ++k) {
    const float4 xk = x4[k];
    const float4 wv = wrow[k];
    acc += xk.x * wv.x + xk.y * wv.y + xk.z * wv.z + xk.w * wv.w;
  }
  out[(size_t)bxy * D_ + tid] = acc;
}

extern "C" void kernel_launch(void* const* d_in, const int* in_sizes, int n_in,
                              void* d_out, int out_size, void* d_ws,
                              size_t ws_size, hipStream_t stream) {
  // setup_inputs order:
  // 0 query (unused), 1 key, 2 value, 3 mask, 4 Wlk, 5 Wrk, 6 Wlv, 7 Wrv,
  // 8 Wq (unused), 9 Wout
  const float* key = (const float*)d_in[1];
  const float* value = (const float*)d_in[2];
  const int* mask = (const int*)d_in[3];
  const float* Wlk = (const float*)d_in[4];
  const float* Wrk = (const float*)d_in[5];
  const float* Wlv = (const float*)d_in[6];
  const float* Wrv = (const float*)d_in[7];
  const float* Wout = (const float*)d_in[9];
  float* out = (float*)d_out;
  float* ws = (float*)d_ws;

  proj4_kernel<<<dim3(R_ / ROWS_PER_BLK, 4), 128, 0, stream>>>(
      key, value, Wlk, Wrk, Wlv, Wrv, ws);
  attn_out_kernel<<<dim3(R_), 128, 0, stream>>>(ws, mask, Wout, out);
}